// Round 10
// baseline (789.704 us; speedup 1.0000x reference)
//
#include <hip/hip_runtime.h>

// SuperpixelPooling: per-(batch, superpixel) mean of 64-dim feature vectors.
// feat[8,512,512,64] f32, labels[8,512,512] i32 in [0,256) -> out[8,256,64] f32.
//
// Round-10: INSTRUMENTED ROUND (deliberate). r8 post-mortem: eliminating the
// per-pixel HBM gather changed nothing (controllable time ~320-390us across
// four structurally different kernels; models predict 60-100us). Since r5 the
// pool kernel has been invisible in rocprof top-5 (five ~330us 2GiB re-poison
// fills saturate it) -> zero direct counters, blind iteration. This round
// doubles ONLY the claim+scatter phase (pass loop; staging/barriers/labels
// run once), halving hist (*0.5f, exact) and cnt (>>1, exact) at flush:
//   read 1: total ~1000-1060, pool VISIBLE with counters -> claim+scatter is
//           the ~300us wall; LDS_BANK_CONFLICT vs VALUBusy vs neither
//           disambiguates conflict / issue / latency-chain.
//   read 2: total ~770-800, pool invisible -> claim+scatter cheap; wall is
//           the staging/barrier path (vmcnt(0) drain at __syncthreads, 1
//           block/CU) -> restructure occupancy/barriers next.
// Either way: claim+scatter cost = total_r10 - 725 (first direct phase
// measurement since r5).
//
// Base structure (r8, unchanged): 512 blocks x 512 thr; block owns 4096-px
// slab; per round 8 waves stage 128 px (32KB) of features into an LDS tile
// (coalesced float4, reg-buffered); wave w owns segments [32w,32w+32);
// ballot+mbcnt rank-compaction -> per-wave queue; full-wave b32 LDS->LDS rmw
// hist[row*64+lane] += tile[px*64+lane] (sequential per pixel = dup-safe;
// rows wave-exclusive = race-free). Flush partials to ws; reduce_kernel sums
// 64 slabs and divides.

#define NBATCH 8
#define NSEG 256
#define NCH 64
#define PPB (512 * 512)                        // 262144 pixels per batch
#define BPB 64                                 // blocks per batch
#define PIX_PER_BLOCK 4096
#define NWAVE 8
#define TILE_PX 128                            // pixels staged per round
#define ROUNDS (PIX_PER_BLOCK / TILE_PX)       // 32
#define PXW (TILE_PX / NWAVE)                  // 16 px staged per wave
#define QMAX 132                               // 128 worst case + 3 pad
#define NROWS (NSEG + NWAVE)                   // 256 real + 8 dummy rows
#define NPASS 2                                // instrumentation multiplier

__global__ __launch_bounds__(512, 2) void pool_kernel(const float* __restrict__ feat,
                                                      const int* __restrict__ sp,
                                                      float* __restrict__ pspart,
                                                      unsigned* __restrict__ pscnt) {
    __shared__ float hist[NROWS * NCH];        // 67.6 KB, rows wave-exclusive
    __shared__ float tile[TILE_PX * NCH];      // 32 KB staged features
    __shared__ int qd[NWAVE][QMAX];            // 4.2 KB
    __shared__ unsigned cnt[NROWS];            // 1.06 KB  -> ~105 KB, 1 blk/CU

    const int b = blockIdx.x >> 6;
    const int slab = blockIdx.x & 63;
    const int tid = threadIdx.x;
    const int lane = tid & 63;
    const int wave = tid >> 6;

    for (int i = tid; i < (NROWS * NCH) / 4; i += 512)
        ((float4*)hist)[i] = make_float4(0.f, 0.f, 0.f, 0.f);
    if (tid < NROWS) cnt[tid] = 0u;

    const int gpix0 = slab * PIX_PER_BLOCK;    // batch-local pixel offset
    const float4* fbase = (const float4*)(feat + ((size_t)b * PPB + gpix0) * NCH);
    const int2* lp2 = (const int2*)(sp + (size_t)b * PPB + gpix0);

    const int dummy_e = (NSEG + wave) << 8;    // dummy row, tile px 0
    int* q = qd[wave];
    float4* t4 = (float4*)tile;
    const int wslice = wave * PXW * 16;        // wave's float4 offset in tile

    // stage: wave's 16 px = 4 KB = 4 coalesced float4 loads per lane
    float4 buf0, buf1, buf2, buf3;
#define STAGE_LOAD(R)                                                         \
    {   const int fb_ = ((R) * TILE_PX) * 16 + wslice;                        \
        buf0 = fbase[fb_ + lane];        buf1 = fbase[fb_ + 64 + lane];       \
        buf2 = fbase[fb_ + 128 + lane];  buf3 = fbase[fb_ + 192 + lane];  }
#define STAGE_WRITE()                                                         \
    {   t4[wslice + lane] = buf0;        t4[wslice + 64 + lane] = buf1;       \
        t4[wslice + 128 + lane] = buf2;  t4[wslice + 192 + lane] = buf3;  }

    STAGE_LOAD(0);
    STAGE_WRITE();                              // hist init + tile ready after
    for (int r = 0; r < ROUNDS; ++r) {
        if (r + 1 < ROUNDS) STAGE_LOAD(r + 1);  // issue early; consumed at end
        __syncthreads();                        // tile (and round-0 hist init) visible

        const int2 L = lp2[r * 64 + lane];      // labels loaded once per round

        // ==== instrumented region: claim + scatter, run NPASS times ====
        for (int pass = 0; pass < NPASS; ++pass) {
            int qn = 0;
#define PUSH(SV, PX)                                                          \
            {                                                                 \
                const int s_ = (SV);                                          \
                const bool own_ = ((s_ >> 5) == wave);                        \
                const unsigned long long m_ = __ballot(own_);                 \
                if (own_) {                                                   \
                    const int r_ = __builtin_amdgcn_mbcnt_hi(                 \
                        (unsigned)(m_ >> 32),                                 \
                        __builtin_amdgcn_mbcnt_lo((unsigned)m_, 0));          \
                    q[qn + r_] = (s_ << 8) | (PX);                            \
                    atomicAdd(&cnt[s_], 1u);                                  \
                }                                                             \
                qn += __builtin_popcountll(m_);                               \
            }
            PUSH(L.x, 2 * lane)
            PUSH(L.y, 2 * lane + 1)
#undef PUSH
            const int npad = (4 - (qn & 3)) & 3;   // pad to x4 (dummy rows)
            if (lane < npad) q[qn + lane] = dummy_e;
            qn += npad;

            // ---- scatter: per-pixel full-wave b32 LDS->LDS rmw ----
            const int ng = qn >> 2;
            for (int g = 0; g < ng; ++g) {
                const int4 e = *(const int4*)&q[g * 4];       // uniform broadcast
                const float v0 = tile[(e.x & 255) * NCH + lane];  // independent
                const float v1 = tile[(e.y & 255) * NCH + lane];  // reads issue
                const float v2 = tile[(e.z & 255) * NCH + lane];  // together
                const float v3 = tile[(e.w & 255) * NCH + lane];
                hist[(e.x >> 8) * NCH + lane] += v0;   // sequential rmw:
                hist[(e.y >> 8) * NCH + lane] += v1;   // in-order within wave,
                hist[(e.z >> 8) * NCH + lane] += v2;   // dup-label safe
                hist[(e.w >> 8) * NCH + lane] += v3;
            }
        }
        // ==== end instrumented region ====

        __syncthreads();                        // all waves done reading tile
        if (r + 1 < ROUNDS) STAGE_WRITE();      // overwrite tile for next round
    }
    __syncthreads();

    // flush per-block partials; undo the NPASS multiplier exactly
    float4* wp = (float4*)(pspart + (size_t)blockIdx.x * (NSEG * NCH));
    const float4* hs = (const float4*)hist;     // first 256 rows contiguous
    for (int i = tid; i < (NSEG * NCH) / 4; i += 512) {
        float4 v = hs[i];
        v.x *= 0.5f; v.y *= 0.5f; v.z *= 0.5f; v.w *= 0.5f;   // exact (pow2)
        wp[i] = v;
    }
    if (tid < NSEG) pscnt[(size_t)blockIdx.x * NSEG + tid] = cnt[tid] >> 1;
}

// One block (1 wave) per (batch, segment): sum 64 slab partials, divide.
__global__ __launch_bounds__(64) void reduce_kernel(const float* __restrict__ pspart,
                                                    const unsigned* __restrict__ pscnt,
                                                    float* __restrict__ out) {
    const int bs = blockIdx.x;                 // b * NSEG + seg
    const int bnum = bs >> 8;
    const int seg = bs & 255;
    const int lane = threadIdx.x;              // 64 = channel

    const float* base = pspart + ((size_t)bnum * BPB * NSEG + seg) * NCH + lane;
    float acc = 0.f;
#pragma unroll
    for (int s = 0; s < BPB; ++s)              // 64 independent 256B row reads
        acc += base[(size_t)s * NSEG * NCH];

    unsigned c = pscnt[((size_t)bnum * BPB + lane) * NSEG + seg];  // lane = slab
    for (int o = 32; o; o >>= 1) c += __shfl_xor(c, o);            // total everywhere

    out[(size_t)bs * NCH + lane] = acc / (float)(c > 0u ? c : 1u);
}

extern "C" void kernel_launch(void* const* d_in, const int* in_sizes, int n_in,
                              void* d_out, int out_size, void* d_ws, size_t ws_size,
                              hipStream_t stream) {
    const float* feat = (const float*)d_in[0];
    const int* sp = (const int*)d_in[1];
    float* out = (float*)d_out;
    float* pspart = (float*)d_ws;                               // 33.5 MB
    unsigned* pscnt = (unsigned*)((char*)d_ws + (size_t)NBATCH * BPB * NSEG * NCH * 4);
    (void)in_sizes; (void)n_in; (void)out_size; (void)ws_size;

    pool_kernel<<<NBATCH * BPB, 512, 0, stream>>>(feat, sp, pspart, pscnt);
    reduce_kernel<<<NBATCH * NSEG, 64, 0, stream>>>(pspart, pscnt, out);
}